// Round 6
// baseline (3408.064 us; speedup 1.0000x reference)
//
#include <hip/hip_runtime.h>
#include <hip/hip_bf16.h>

// B=8, C_IN=C_OUT=64, H=W=64, K=3, N=9, PAD=1 -> padded coords in [0,65]
// Round 6: identical semantics to R5 (triple-verified), output written as FP32
// (the reference's output dtype -- f32 in, f32 out).

// ---------- K1: offset conv: offs[b][o][h][w], o in [0,18) ----------
__global__ __launch_bounds__(256) void k1_offsets(
    const float* __restrict__ x,      // [8][64][64][64]
    const float* __restrict__ woff,   // [18][64][3][3]
    const float* __restrict__ boff,   // [18]
    float* __restrict__ offs) {       // [8][18][64][64]
  int idx = blockIdx.x * 256 + threadIdx.x;   // < 589824
  int w = idx % 64;
  int h = (idx / 64) % 64;
  int o = (idx / 4096) % 18;
  int b = idx / 73728;

  float acc = boff[o];
  for (int c = 0; c < 64; ++c) {
    for (int kh = 0; kh < 3; ++kh) {
      int ih = h + kh - 1;
      if (ih < 0 || ih > 63) continue;
      for (int kw = 0; kw < 3; ++kw) {
        int iw = w + kw - 1;
        if (iw < 0 || iw > 63) continue;
        acc += x[((b * 64 + c) * 64 + ih) * 64 + iw]
             * woff[((o * 64 + c) * 3 + kh) * 3 + kw];
      }
    }
  }
  offs[idx] = acc;
}

// ---------- K2: brute-force deformable sample + final conv ----------
// one thread per output element (b, co, h, w); 2097152 threads
__global__ __launch_bounds__(256) void k2_brute(
    const float* __restrict__ x,      // [8][64][64][64]
    const float* __restrict__ offs,   // [8][18][64][64]
    const float* __restrict__ wconv,  // [64][64][3][3]
    float* __restrict__ out) {        // [8][64][64][64] fp32
  int idx = blockIdx.x * 256 + threadIdx.x;   // < 2097152
  int w  = idx % 64;
  int h  = (idx / 64) % 64;
  int co = (idx / 4096) % 64;
  int b  = idx / 262144;

  const float* xb = x + b * 262144;           // [c][64][64]
  float acc = 0.f;

  for (int n = 0; n < 9; ++n) {
    // p = p0 + pn + offset   (padded 1-based coords)
    float ox = offs[((b * 18 + n) * 64 + h) * 64 + w];
    float oy = offs[((b * 18 + 9 + n) * 64 + h) * 64 + w];
    float px = (float)(h + 1) + (float)(n / 3 - 1) + ox;
    float py = (float)(w + 1) + (float)(n % 3 - 1) + oy;

    float fx = floorf(px), fy = floorf(py);
    float qltx = fminf(fmaxf(fx,       0.f), 65.f);
    float qlty = fminf(fmaxf(fy,       0.f), 65.f);
    float qrbx = fminf(fmaxf(fx + 1.f, 0.f), 65.f);
    float qrby = fminf(fmaxf(fy + 1.f, 0.f), 65.f);
    float pxc  = fminf(fmaxf(px, 0.f), 65.f);
    float pyc  = fminf(fmaxf(py, 0.f), 65.f);

    float glt = (1.f + qltx - pxc) * (1.f + qlty - pyc);
    float grb = (1.f - qrbx + pxc) * (1.f - qrby + pyc);
    float glb = (1.f + qltx - pxc) * (1.f - qrby + pyc);
    float grt = (1.f - qrbx + pxc) * (1.f + qlty - pyc);

    int ilt = (int)qltx, jlt = (int)qlty;
    int irb = (int)qrbx, jrb = (int)qrby;
    // padded coord i in [1,64] maps to x[i-1]; 0 and 65 are the zero pad
    bool vi_lt = (ilt >= 1 && ilt <= 64), vj_lt = (jlt >= 1 && jlt <= 64);
    bool vi_rb = (irb >= 1 && irb <= 64), vj_rb = (jrb >= 1 && jrb <= 64);
    int o_lt = (ilt - 1) * 64 + (jlt - 1);
    int o_rb = (irb - 1) * 64 + (jrb - 1);
    int o_lb = (ilt - 1) * 64 + (jrb - 1);
    int o_rt = (irb - 1) * 64 + (jlt - 1);

    const float* wc = wconv + co * 576 + n;   // stride 9 over c

    for (int c = 0; c < 64; ++c) {
      const float* xc = xb + c * 4096;
      float vlt = (vi_lt && vj_lt) ? xc[o_lt] : 0.f;
      float vrb = (vi_rb && vj_rb) ? xc[o_rb] : 0.f;
      float vlb = (vi_lt && vj_rb) ? xc[o_lb] : 0.f;
      float vrt = (vi_rb && vj_lt) ? xc[o_rt] : 0.f;
      float xo = glt * vlt + grb * vrb + glb * vlb + grt * vrt;
      acc += xo * wc[c * 9];
    }
  }
  out[idx] = acc;
}

extern "C" void kernel_launch(void* const* d_in, const int* in_sizes, int n_in,
                              void* d_out, int out_size, void* d_ws, size_t ws_size,
                              hipStream_t stream) {
  const float *x = nullptr, *woff = nullptr, *boff = nullptr, *wconv = nullptr;
  for (int i = 0; i < n_in; ++i) {
    switch (in_sizes[i]) {
      case 2097152: x     = (const float*)d_in[i]; break;
      case 10368:   woff  = (const float*)d_in[i]; break;
      case 18:      boff  = (const float*)d_in[i]; break;
      case 36864:   wconv = (const float*)d_in[i]; break;
      default: break;
    }
  }
  if (!x)     x     = (const float*)d_in[0];
  if (!woff)  woff  = (const float*)d_in[1];
  if (!boff)  boff  = (const float*)d_in[2];
  if (!wconv) wconv = (const float*)d_in[3];
  float* out = (float*)d_out;

  float* offs = (float*)d_ws;   // 589824 floats = 2.36 MB

  k1_offsets<<<2304, 256, 0, stream>>>(x, woff, boff, offs);
  k2_brute<<<8192, 256, 0, stream>>>(x, offs, wconv, out);
}

// Round 7
// 355.544 us; speedup vs baseline: 9.5855x; 9.5855x over previous
//
#include <hip/hip_runtime.h>
#include <hip/hip_bf16.h>

// B=8, C_IN=C_OUT=64, H=W=64, K=3, N=9, PAD=1; padded coords in [0,65]
// f32 in, f32 out (verified R6). Semantics identical to R5/R6 (triple-verified).

typedef unsigned int u32;

// ---------- K1: offset conv: offs[b][o][h][w], o in [0,18) ----------
__global__ __launch_bounds__(256) void k1_offsets(
    const float* __restrict__ x,      // [8][64][64][64]
    const float* __restrict__ woff,   // [18][64][3][3]
    const float* __restrict__ boff,   // [18]
    float* __restrict__ offs) {       // [8][18][64][64]
  int idx = blockIdx.x * 256 + threadIdx.x;   // < 589824
  int w = idx % 64;
  int h = (idx / 64) % 64;
  int o = (idx / 4096) % 18;
  int b = idx / 73728;

  float acc = boff[o];
  for (int c = 0; c < 64; ++c) {
    const float* xc = x + ((b * 64 + c) * 64) * 64;
    const float* wc = woff + (o * 64 + c) * 9;
    #pragma unroll
    for (int kh = 0; kh < 3; ++kh) {
      int ih = h + kh - 1;
      if (ih < 0 || ih > 63) continue;
      const float* xr = xc + ih * 64 + w;
      float xl = (w > 0)  ? xr[-1] : 0.f;
      float xm = xr[0];
      float xr_ = (w < 63) ? xr[1] : 0.f;
      acc += xl * wc[kh * 3] + xm * wc[kh * 3 + 1] + xr_ * wc[kh * 3 + 2];
    }
  }
  offs[idx] = acc;
}

// ---------- K2: fused sample + final conv, one block per (b,h) ----------
// 512 blocks x 256 threads (4 waves). lane = w. Each wave owns 16 co.
__global__ __launch_bounds__(256) void k2_fused(
    const float* __restrict__ x,      // [8][64][64][64]
    const float* __restrict__ offs,   // [8][18][64][64]
    const float* __restrict__ wconv,  // [64][576] (=[64][64][3][3])
    float* __restrict__ out) {        // [8][64][64][64]
  __shared__ float4 gw_t[9 * 64];     // [n][w] bilinear weights (lt, rb, lb, rt)
  __shared__ u32    qq_t[9 * 64];     // [n][w] packed clamped corners
  __shared__ float  xo[144 * 66];     // slice samples [cl*9+n][w], w padded to 66

  int bh = blockIdx.x;
  int b = bh >> 6, h = bh & 63;
  int t = threadIdx.x;
  int wlane = t & 63;
  int wv    = t >> 6;        // wave id 0..3
  int cobase = wv * 16;

  // ---- Phase C: corners + bilinear weights per (w, n) ----
  const float* offb = offs + b * 18 * 4096 + h * 64;
  for (int p = t; p < 576; p += 256) {
    int w = p >> 4 == 0 ? 0 : 0;  // (placeholder avoided below)
    int n = p / 64;               // transposed: p = n*64 + w
    int ww = p & 63;
    float ox = offb[n * 4096 + ww];
    float oy = offb[(9 + n) * 4096 + ww];
    float px = (float)(h + (n / 3)) + ox;   // (h+1)+(n/3-1)+ox
    float py = (float)(ww + (n % 3)) + oy;
    float fx = floorf(px), fy = floorf(py);
    float pxc  = fminf(fmaxf(px, 0.f), 65.f);
    float pyc  = fminf(fmaxf(py, 0.f), 65.f);
    float fltx = fminf(fmaxf(fx, 0.f), 65.f);
    float flty = fminf(fmaxf(fy, 0.f), 65.f);
    float frbx = fminf(fmaxf(fx + 1.f, 0.f), 65.f);
    float frby = fminf(fmaxf(fy + 1.f, 0.f), 65.f);
    float ax = 1.f + fltx - pxc, bx = 1.f - frbx + pxc;
    float ay = 1.f + flty - pyc, by = 1.f - frby + pyc;
    gw_t[p] = make_float4(ax * ay, bx * by, ax * by, bx * ay);  // glt, grb, glb, grt
    qq_t[p] = (u32)fltx | ((u32)flty << 8) | ((u32)frbx << 16) | ((u32)frby << 24);
  }
  __syncthreads();

  float acc[16];
  #pragma unroll
  for (int i = 0; i < 16; ++i) acc[i] = 0.f;

  const float*  xb = x + b * 262144;
  const float4* w4 = (const float4*)wconv;   // [64][144]

  for (int s = 0; s < 4; ++s) {
    // ---- sample slice s: channels s*16 .. s*16+15; lane = w ----
    for (int n = 0; n < 9; ++n) {
      float4 g = gw_t[n * 64 + wlane];
      u32 q    = qq_t[n * 64 + wlane];
      int ilt = q & 255, jlt = (q >> 8) & 255, irb = (q >> 16) & 255, jrb = q >> 24;
      bool vi_lt = (ilt >= 1 && ilt <= 64), vj_lt = (jlt >= 1 && jlt <= 64);
      bool vi_rb = (irb >= 1 && irb <= 64), vj_rb = (jrb >= 1 && jrb <= 64);
      int o_lt = (ilt - 1) * 64 + (jlt - 1);
      int o_rb = (irb - 1) * 64 + (jrb - 1);
      int o_lb = (ilt - 1) * 64 + (jrb - 1);
      int o_rt = (irb - 1) * 64 + (jlt - 1);
      #pragma unroll
      for (int j = 0; j < 4; ++j) {
        int cl = wv + 4 * j;            // 0..15
        const float* xc = xb + (s * 16 + cl) * 4096;
        float vlt = (vi_lt && vj_lt) ? xc[o_lt] : 0.f;
        float vrb = (vi_rb && vj_rb) ? xc[o_rb] : 0.f;
        float vlb = (vi_lt && vj_rb) ? xc[o_lb] : 0.f;
        float vrt = (vi_rb && vj_lt) ? xc[o_rt] : 0.f;
        xo[(cl * 9 + n) * 66 + wlane] = g.x * vlt + g.y * vrb + g.z * vlb + g.w * vrt;
      }
    }
    __syncthreads();

    // ---- dot: acc[i] += xo[k][wlane] . W[cobase+i][s*144 + k] ----
    for (int k4 = 0; k4 < 36; ++k4) {
      float xv0 = xo[(k4 * 4 + 0) * 66 + wlane];
      float xv1 = xo[(k4 * 4 + 1) * 66 + wlane];
      float xv2 = xo[(k4 * 4 + 2) * 66 + wlane];
      float xv3 = xo[(k4 * 4 + 3) * 66 + wlane];
      #pragma unroll
      for (int i = 0; i < 16; ++i) {
        float4 wr = w4[(cobase + i) * 144 + s * 36 + k4];
        acc[i] += xv0 * wr.x + xv1 * wr.y + xv2 * wr.z + xv3 * wr.w;
      }
    }
    __syncthreads();
  }

  float* ob = out + b * 262144 + h * 64 + wlane;
  #pragma unroll
  for (int i = 0; i < 16; ++i)
    ob[(cobase + i) * 4096] = acc[i];
}

extern "C" void kernel_launch(void* const* d_in, const int* in_sizes, int n_in,
                              void* d_out, int out_size, void* d_ws, size_t ws_size,
                              hipStream_t stream) {
  const float *x = nullptr, *woff = nullptr, *boff = nullptr, *wconv = nullptr;
  for (int i = 0; i < n_in; ++i) {
    switch (in_sizes[i]) {
      case 2097152: x     = (const float*)d_in[i]; break;
      case 10368:   woff  = (const float*)d_in[i]; break;
      case 18:      boff  = (const float*)d_in[i]; break;
      case 36864:   wconv = (const float*)d_in[i]; break;
      default: break;
    }
  }
  if (!x)     x     = (const float*)d_in[0];
  if (!woff)  woff  = (const float*)d_in[1];
  if (!boff)  boff  = (const float*)d_in[2];
  if (!wconv) wconv = (const float*)d_in[3];
  float* out = (float*)d_out;

  float* offs = (float*)d_ws;   // 589824 floats = 2.36 MB

  k1_offsets<<<2304, 256, 0, stream>>>(x, woff, boff, offs);
  k2_fused<<<512, 256, 0, stream>>>(x, offs, wconv, out);
}

// Round 8
// 202.721 us; speedup vs baseline: 16.8116x; 1.7539x over previous
//
#include <hip/hip_runtime.h>
#include <hip/hip_bf16.h>

// B=8, C_IN=C_OUT=64, H=W=64, K=3, N=9, PAD=1; padded coords in [0,65]
// f32 in, f32 out (verified R6/R7). Semantics identical to R5/R6/R7.

typedef unsigned int u32;

// ---------- K1: offset conv, one block per (b,h) row ----------
// 512 blocks x 256 threads. Stage x rows h-1..h+1 (all 64 c) in LDS,
// register-block all 18 o-accumulators per thread (lane = w, wave owns 16 c).
__global__ __launch_bounds__(256) void k1_offsets(
    const float* __restrict__ x,      // [8][64][64][64]
    const float* __restrict__ woff,   // [18][64][3][3]
    const float* __restrict__ boff,   // [18]
    float* __restrict__ offs) {       // [8][18][64][64]
  __shared__ float xs[3 * 64 * 64];   // [kh][c][w] 49152B; reused for partials

  int bh = blockIdx.x;
  int b = bh >> 6, h = bh & 63;
  int t = threadIdx.x;

  // stage 3 rows, all channels (coalesced)
  const float* xb = x + b * 262144;
  for (int i = t; i < 12288; i += 256) {
    int kh = i >> 12, c = (i >> 6) & 63, w = i & 63;
    int hh = h + kh - 1;
    xs[i] = (hh >= 0 && hh < 64) ? xb[c * 4096 + hh * 64 + w] : 0.f;
  }
  __syncthreads();

  int w  = t & 63;
  int wv = __builtin_amdgcn_readfirstlane(t >> 6);  // wave id 0..3, scalar
  bool lf = w > 0, rt = w < 63;

  float acc[18];
  #pragma unroll
  for (int o = 0; o < 18; ++o) acc[o] = 0.f;

  for (int cl = 0; cl < 16; ++cl) {
    int c = wv * 16 + cl;
    float v[9];
    #pragma unroll
    for (int kh = 0; kh < 3; ++kh) {
      const float* base = xs + kh * 4096 + c * 64;
      v[kh * 3 + 0] = lf ? base[w - 1] : 0.f;
      v[kh * 3 + 1] = base[w];
      v[kh * 3 + 2] = rt ? base[w + 1] : 0.f;
    }
    const float* wc = woff + c * 9;   // + o*576
    #pragma unroll
    for (int o = 0; o < 18; ++o) {
      const float* wo = wc + o * 576;
      float a = acc[o];
      a += v[0] * wo[0] + v[1] * wo[1] + v[2] * wo[2];
      a += v[3] * wo[3] + v[4] * wo[4] + v[5] * wo[5];
      a += v[6] * wo[6] + v[7] * wo[7] + v[8] * wo[8];
      acc[o] = a;
    }
  }
  __syncthreads();   // xs dead; reuse for per-wave partials [wv][o][w]

  #pragma unroll
  for (int o = 0; o < 18; ++o)
    xs[wv * 1152 + o * 64 + w] = acc[o];
  __syncthreads();

  float* ob = offs + b * 73728 + h * 64;
  for (int i = t; i < 1152; i += 256) {
    int o = i >> 6, ww = i & 63;
    float s = xs[i] + xs[1152 + i] + xs[2304 + i] + xs[3456 + i] + boff[o];
    ob[o * 4096 + ww] = s;
  }
}

// ---------- K2: fused sample + final conv, one block per (b,h) ----------
// 512 blocks x 512 threads (8 waves). lane = w. Each wave owns 8 co.
__global__ __launch_bounds__(512) void k2_fused(
    const float* __restrict__ x,      // [8][64][64][64]
    const float* __restrict__ offs,   // [8][18][64][64]
    const float* __restrict__ wconv,  // [64][576]
    float* __restrict__ out) {        // [8][64][64][64]
  __shared__ float4 gw_t[9 * 64];     // [n][w] bilinear weights (lt, rb, lb, rt)
  __shared__ u32    qq_t[9 * 64];     // [n][w] packed clamped corners
  __shared__ float  xo[144 * 66];     // slice samples [cl*9+n][w], w padded to 66

  int bh = blockIdx.x;
  int b = bh >> 6, h = bh & 63;
  int t = threadIdx.x;
  int wlane = t & 63;
  int wv = __builtin_amdgcn_readfirstlane(t >> 6);   // 0..7
  int cobase = wv * 8;

  // ---- Phase C: corners + bilinear weights per (w, n), transposed [n][w] ----
  const float* offb = offs + b * 73728 + h * 64;
  for (int p = t; p < 576; p += 512) {
    int n  = p >> 6;       // p = n*64 + w
    int ww = p & 63;
    float ox = offb[n * 4096 + ww];
    float oy = offb[(9 + n) * 4096 + ww];
    float px = (float)(h + (n / 3)) + ox;   // (h+1)+(n/3-1)+ox
    float py = (float)(ww + (n % 3)) + oy;
    float fx = floorf(px), fy = floorf(py);
    float pxc  = fminf(fmaxf(px, 0.f), 65.f);
    float pyc  = fminf(fmaxf(py, 0.f), 65.f);
    float fltx = fminf(fmaxf(fx, 0.f), 65.f);
    float flty = fminf(fmaxf(fy, 0.f), 65.f);
    float frbx = fminf(fmaxf(fx + 1.f, 0.f), 65.f);
    float frby = fminf(fmaxf(fy + 1.f, 0.f), 65.f);
    float ax = 1.f + fltx - pxc, bx = 1.f - frbx + pxc;
    float ay = 1.f + flty - pyc, by = 1.f - frby + pyc;
    gw_t[p] = make_float4(ax * ay, bx * by, ax * by, bx * ay);  // glt, grb, glb, grt
    qq_t[p] = (u32)fltx | ((u32)flty << 8) | ((u32)frbx << 16) | ((u32)frby << 24);
  }
  __syncthreads();

  float acc[8];
  #pragma unroll
  for (int i = 0; i < 8; ++i) acc[i] = 0.f;

  const float*  xb = x + b * 262144;
  const float4* w4 = (const float4*)wconv;   // [64][144]

  for (int s = 0; s < 4; ++s) {
    // ---- sample slice s: channels s*16 .. s*16+15; 2 c per thread ----
    for (int n = 0; n < 9; ++n) {
      float4 g = gw_t[n * 64 + wlane];
      u32 q    = qq_t[n * 64 + wlane];
      int ilt = q & 255, jlt = (q >> 8) & 255, irb = (q >> 16) & 255, jrb = q >> 24;
      bool vi_lt = (ilt >= 1 && ilt <= 64), vj_lt = (jlt >= 1 && jlt <= 64);
      bool vi_rb = (irb >= 1 && irb <= 64), vj_rb = (jrb >= 1 && jrb <= 64);
      int o_lt = (ilt - 1) * 64 + (jlt - 1);
      int o_rb = (irb - 1) * 64 + (jrb - 1);
      int o_lb = (ilt - 1) * 64 + (jrb - 1);
      int o_rt = (irb - 1) * 64 + (jlt - 1);
      #pragma unroll
      for (int j = 0; j < 2; ++j) {
        int cl = wv * 2 + j;            // 0..15
        const float* xc = xb + (s * 16 + cl) * 4096;
        float vlt = (vi_lt && vj_lt) ? xc[o_lt] : 0.f;
        float vrb = (vi_rb && vj_rb) ? xc[o_rb] : 0.f;
        float vlb = (vi_lt && vj_rb) ? xc[o_lb] : 0.f;
        float vrt = (vi_rb && vj_lt) ? xc[o_rt] : 0.f;
        xo[(cl * 9 + n) * 66 + wlane] = g.x * vlt + g.y * vrb + g.z * vlb + g.w * vrt;
      }
    }
    __syncthreads();

    // ---- dot: acc[i] += xo[k][wlane] . W[cobase+i][s*144 + k] ----
    for (int k4 = 0; k4 < 36; ++k4) {
      float xv0 = xo[(k4 * 4 + 0) * 66 + wlane];
      float xv1 = xo[(k4 * 4 + 1) * 66 + wlane];
      float xv2 = xo[(k4 * 4 + 2) * 66 + wlane];
      float xv3 = xo[(k4 * 4 + 3) * 66 + wlane];
      #pragma unroll
      for (int i = 0; i < 8; ++i) {
        float4 wr = w4[(cobase + i) * 144 + s * 36 + k4];
        acc[i] += xv0 * wr.x + xv1 * wr.y + xv2 * wr.z + xv3 * wr.w;
      }
    }
    __syncthreads();
  }

  float* ob = out + b * 262144 + h * 64 + wlane;
  #pragma unroll
  for (int i = 0; i < 8; ++i)
    ob[(cobase + i) * 4096] = acc[i];
}

extern "C" void kernel_launch(void* const* d_in, const int* in_sizes, int n_in,
                              void* d_out, int out_size, void* d_ws, size_t ws_size,
                              hipStream_t stream) {
  const float *x = nullptr, *woff = nullptr, *boff = nullptr, *wconv = nullptr;
  for (int i = 0; i < n_in; ++i) {
    switch (in_sizes[i]) {
      case 2097152: x     = (const float*)d_in[i]; break;
      case 10368:   woff  = (const float*)d_in[i]; break;
      case 18:      boff  = (const float*)d_in[i]; break;
      case 36864:   wconv = (const float*)d_in[i]; break;
      default: break;
    }
  }
  if (!x)     x     = (const float*)d_in[0];
  if (!woff)  woff  = (const float*)d_in[1];
  if (!boff)  boff  = (const float*)d_in[2];
  if (!wconv) wconv = (const float*)d_in[3];
  float* out = (float*)d_out;

  float* offs = (float*)d_ws;   // 589824 floats = 2.36 MB

  k1_offsets<<<512, 256, 0, stream>>>(x, woff, boff, offs);
  k2_fused<<<512, 512, 0, stream>>>(x, offs, wconv, out);
}